// Round 4
// baseline (120.282 us; speedup 1.0000x reference)
//
#include <hip/hip_runtime.h>
#include <hip/hip_bf16.h>

#define F 64
#define R 64
#define O 64
#define BLOCK_B 64   // batch rows per block (1024 threads, 16 waves)

typedef short bf16x8 __attribute__((ext_vector_type(8)));
typedef float f32x4 __attribute__((ext_vector_type(4)));
typedef float f32x2 __attribute__((ext_vector_type(2)));

static __device__ __forceinline__ short f2bf(float f) {
    unsigned u = __builtin_bit_cast(unsigned, f);
    unsigned r = (u + 0x7fffu + ((u >> 16) & 1u)) >> 16;
    return (short)r;
}

// ---------------------------------------------------------------------------
// Prep kernel, 66 blocks x 256.
// Blocks 0..64 (= f): pack W f-slab -> Wpk bf16 in MFMA B-fragment order,
//   fully coalesced via an LDS bounce.
//   Wpk bf16x8 index: ((nt*65 + f)*2 + kk)*64 + lane
//   element j = W[o][f*64 + r], o = nt*16+(lane&15), r = (lane>>4)*8 + j + kk*32
// Block 65: prm[u] = {s, mn*s, t, c}, u = f*64 + r,  s = sqrt(log2 e)/std.
// ---------------------------------------------------------------------------
__global__ __launch_bounds__(256) void fq_prep(
        const float* __restrict__ tt, const float* __restrict__ mean,
        const float* __restrict__ std_, const float* __restrict__ W,
        float* __restrict__ prm, unsigned short* __restrict__ Wpk)
{
    const int blk = blockIdx.x;
    const int t   = threadIdx.x;
    if (blk < 65) {
        const int f = blk;
        __shared__ __align__(16) float ws[64][68];
        // coalesced load of the 64x64 slab W[o][f*64 + r]
#pragma unroll
        for (int i = 0; i < 16; ++i) {
            const int o = i * 4 + (t >> 6);
            const int r = t & 63;
            ws[o][r] = W[(size_t)o * 4160 + f * 64 + r];
        }
        __syncthreads();
        // pack 512 fragments (2 per thread), contiguous 16-B stores
#pragma unroll
        for (int half = 0; half < 2; ++half) {
            const int u8   = half * 256 + t;
            const int lane = u8 & 63;
            const int kk   = (u8 >> 6) & 1;
            const int nt   = u8 >> 7;
            const int o    = nt * 16 + (lane & 15);
            const int rb   = ((lane >> 4) << 3) + kk * 32;
            f32x4 a = *(const f32x4*)&ws[o][rb];
            f32x4 b = *(const f32x4*)&ws[o][rb + 4];
            unsigned short v[8];
            v[0] = (unsigned short)f2bf(a[0]); v[1] = (unsigned short)f2bf(a[1]);
            v[2] = (unsigned short)f2bf(a[2]); v[3] = (unsigned short)f2bf(a[3]);
            v[4] = (unsigned short)f2bf(b[0]); v[5] = (unsigned short)f2bf(b[1]);
            v[6] = (unsigned short)f2bf(b[2]); v[7] = (unsigned short)f2bf(b[3]);
            const int dst = ((nt * 65 + f) * 2 + kk) * 64 + lane;
            *(bf16x8*)(Wpk + (size_t)dst * 8) = *(bf16x8*)v;
        }
    } else {
#pragma unroll
        for (int i = 0; i < 16; ++i) {
            const int u = i * 256 + t;
            float sd = std_[u];
            float mn = mean[u];
            float th = tanhf(tt[u]);
            float s  = 1.2011224087864498f / sd;  // sqrt(log2(e)) / std
            float4 p;
            p.x = s;
            p.y = mn * s;
            p.z = th;
            p.w = 0.5f * (1.0f - th);
            ((float4*)prm)[u] = p;
        }
    }
}

// ---------------------------------------------------------------------------
// Main fused kernel: block = 64 batch rows, 1024 threads (16 waves).
// Stage 0: stage X slab transposed into LDS xt[f][row].
// Stage 1: wave w computes fire for rows 4w..4w+3 (lane = rule r), pk-f32 math,
//          x read as broadcast ds_read_b64 pairs from xt.
// Stage 2: wave w -> nt = w>>2, mrow = w&3: 16x16 tile rows [16*mrow, +16) x
//          cols [16*nt, +16). A = bf16(normalized fire), constant over f.
//          Per f: U = wn @ B_f (2 MFMA), acc += x_f * U (4 fmac).
//          The 4 waves of each nt issue identical Wp addresses -> L1 sharing.
// ---------------------------------------------------------------------------
__global__ __launch_bounds__(1024, 8) void fq_main(
        const float* __restrict__ X,
        const float4* __restrict__ prm,
        const bf16x8* __restrict__ Wp,
        float* __restrict__ out)
{
    __shared__ __align__(16) float xt[64][68];        // [f][row]
    __shared__ __align__(16) float fire_lds[64][68];  // [row][r]
    __shared__ float rinv[BLOCK_B];

    const int t    = threadIdx.x;
    const int lane = t & 63;
    const int w    = __builtin_amdgcn_readfirstlane(t >> 6);  // wave 0..15
    const int b0   = blockIdx.x * BLOCK_B;

    // ---- stage 0: transpose X slab into xt ---------------------------------
    {
        const int row = t & 63;
        const int f4  = (t >> 6) * 4;   // 0..60
        float4 xv = *(const float4*)(X + (size_t)(b0 + row) * 64 + f4);
        xt[f4 + 0][row] = xv.x;
        xt[f4 + 1][row] = xv.y;
        xt[f4 + 2][row] = xv.z;
        xt[f4 + 3][row] = xv.w;
    }
    __syncthreads();

    // ---- stage 1: firing strengths, rows 4w..4w+3, lane = r ----------------
    {
        f32x2 fire2[2] = {(f32x2){1.f, 1.f}, (f32x2){1.f, 1.f}};
        const int r0 = 4 * w;
#pragma unroll 4
        for (int f = 0; f < F; ++f) {
            float4 p = prm[f * 64 + lane];    // {s, mn*s, t, c}
            f32x2 x01 = *(const f32x2*)&xt[f][r0];      // broadcast ds_read_b64
            f32x2 x23 = *(const f32x2*)&xt[f][r0 + 2];
            f32x2 z0, z1;
            z0.x = __builtin_fmaf(x01.x, p.x, -p.y);
            z0.y = __builtin_fmaf(x01.y, p.x, -p.y);
            z1.x = __builtin_fmaf(x23.x, p.x, -p.y);
            z1.y = __builtin_fmaf(x23.y, p.x, -p.y);
            f32x2 nz0 = -(z0 * z0), nz1 = -(z1 * z1);
            f32x2 g0, g1;
            g0.x = __builtin_amdgcn_exp2f(nz0.x);
            g0.y = __builtin_amdgcn_exp2f(nz0.y);
            g1.x = __builtin_amdgcn_exp2f(nz1.x);
            g1.y = __builtin_amdgcn_exp2f(nz1.y);
            f32x2 t2 = (f32x2){p.z, p.z};
            f32x2 c2 = (f32x2){p.w, p.w};
            fire2[0] *= g0 * t2 + c2;
            fire2[1] *= g1 * t2 + c2;
        }
        fire_lds[r0 + 0][lane] = fire2[0].x;
        fire_lds[r0 + 1][lane] = fire2[0].y;
        fire_lds[r0 + 2][lane] = fire2[1].x;
        fire_lds[r0 + 3][lane] = fire2[1].y;
    }
    __syncthreads();

    // ---- row sums: 8 threads per row, shuffle-reduce -----------------------
    if (t < 512) {
        const int row = t >> 3;
        const int c8  = (t & 7) * 8;
        f32x4 s0 = *(const f32x4*)&fire_lds[row][c8];
        f32x4 s1 = *(const f32x4*)&fire_lds[row][c8 + 4];
        float s = (s0[0] + s0[1]) + (s0[2] + s0[3]) +
                  (s1[0] + s1[1]) + (s1[2] + s1[3]);
        s += __shfl_xor(s, 1);
        s += __shfl_xor(s, 2);
        s += __shfl_xor(s, 4);
        if ((t & 7) == 0) rinv[row] = 1.0f / s;
    }
    __syncthreads();

    // ---- stage 2: 16x16 tile per wave --------------------------------------
    const int m_in  = lane & 15;
    const int quad  = lane >> 4;
    const int nt    = w >> 2;
    const int mrow  = w & 3;
    const int myrow = 16 * mrow + m_in;
    const float rs  = rinv[myrow];
    const int q8    = quad * 8;

    bf16x8 wfrag[2];
#pragma unroll
    for (int kk = 0; kk < 2; ++kk)
#pragma unroll
        for (int j = 0; j < 8; ++j)
            wfrag[kk][j] = f2bf(fire_lds[myrow][q8 + j + kk * 32] * rs);

    const bf16x8* wpb = Wp + (size_t)(nt * 130) * 64 + lane;
    const int xoff = 16 * mrow + quad * 4;

    f32x4 acc = (f32x4){0.f, 0.f, 0.f, 0.f};
    const f32x4 z4 = (f32x4){0.f, 0.f, 0.f, 0.f};

#pragma unroll 4
    for (int f = 0; f < F; ++f) {
        bf16x8 bb0 = wpb[(2 * f) * 64];
        bf16x8 bb1 = wpb[(2 * f + 1) * 64];
        f32x4 U = __builtin_amdgcn_mfma_f32_16x16x32_bf16(wfrag[0], bb0, z4, 0, 0, 0);
        U = __builtin_amdgcn_mfma_f32_16x16x32_bf16(wfrag[1], bb1, U, 0, 0, 0);
        f32x4 xv = *(const f32x4*)&xt[f][xoff];   // broadcast ds_read_b128
#pragma unroll
        for (int reg = 0; reg < 4; ++reg)
            acc[reg] = __builtin_fmaf(xv[reg], U[reg], acc[reg]);
    }

    // bias column (Xa[:,64] = 1): acc += wn @ B_64
    {
        bf16x8 bb0 = wpb[128 * 64];
        bf16x8 bb1 = wpb[129 * 64];
        f32x4 U = __builtin_amdgcn_mfma_f32_16x16x32_bf16(wfrag[0], bb0, z4, 0, 0, 0);
        U = __builtin_amdgcn_mfma_f32_16x16x32_bf16(wfrag[1], bb1, U, 0, 0, 0);
#pragma unroll
        for (int reg = 0; reg < 4; ++reg)
            acc[reg] += U[reg];
    }

    // epilogue: C/D layout col = lane&15, row = quad*4 + reg
#pragma unroll
    for (int reg = 0; reg < 4; ++reg) {
        const int row = b0 + 16 * mrow + quad * 4 + reg;
        out[(size_t)row * 64 + nt * 16 + m_in] = acc[reg];
    }
}

extern "C" void kernel_launch(void* const* d_in, const int* in_sizes, int n_in,
                              void* d_out, int out_size, void* d_ws, size_t ws_size,
                              hipStream_t stream) {
    const float* X    = (const float*)d_in[0];
    const float* tt   = (const float*)d_in[1];
    const float* mean = (const float*)d_in[2];
    const float* std_ = (const float*)d_in[3];
    const float* W    = (const float*)d_in[4];
    float* out = (float*)d_out;

    // workspace: prm (float4 x 4096 = 64 KiB) | Wpk (bf16 x 65*512*8 = 520 KiB)
    float* prm = (float*)d_ws;
    unsigned short* Wpk = (unsigned short*)((char*)d_ws + 65536);

    fq_prep<<<66, 256, 0, stream>>>(tt, mean, std_, W, prm, Wpk);

    const int nblocks = 32768 / BLOCK_B;  // 512 blocks x 1024 threads = 8192 waves
    fq_main<<<nblocks, 1024, 0, stream>>>(X, (const float4*)prm,
                                          (const bf16x8*)Wpk, out);
}

// Round 5
// 117.411 us; speedup vs baseline: 1.0245x; 1.0245x over previous
//
#include <hip/hip_runtime.h>
#include <hip/hip_bf16.h>

#define F 64
#define R 64
#define O 64
#define BLOCK_B 64   // batch rows per block (256 threads, 4 waves)

typedef short bf16x8 __attribute__((ext_vector_type(8)));
typedef float f32x4 __attribute__((ext_vector_type(4)));
typedef float f32x2 __attribute__((ext_vector_type(2)));

static __device__ __forceinline__ short f2bf(float f) {
    unsigned u = __builtin_bit_cast(unsigned, f);
    unsigned r = (u + 0x7fffu + ((u >> 16) & 1u)) >> 16;
    return (short)r;
}

// ---------------------------------------------------------------------------
// Prep kernel, 66 blocks x 256 (unchanged from round 4 — works, cheap).
// Blocks 0..64 (= f): pack W f-slab -> Wpk bf16 in MFMA B-fragment order.
//   Wpk bf16x8 index: ((nt*65 + f)*2 + kk)*64 + lane
//   element j = W[o][f*64 + r], o = nt*16+(lane&15), r = (lane>>4)*8 + j + kk*32
// Block 65: prm[u] = {s, mn*s, t, c}, u = f*64 + r,  s = sqrt(log2 e)/std.
// ---------------------------------------------------------------------------
__global__ __launch_bounds__(256) void fq_prep(
        const float* __restrict__ tt, const float* __restrict__ mean,
        const float* __restrict__ std_, const float* __restrict__ W,
        float* __restrict__ prm, unsigned short* __restrict__ Wpk)
{
    const int blk = blockIdx.x;
    const int t   = threadIdx.x;
    if (blk < 65) {
        const int f = blk;
        __shared__ __align__(16) float ws[64][68];
#pragma unroll
        for (int i = 0; i < 16; ++i) {
            const int o = i * 4 + (t >> 6);
            const int r = t & 63;
            ws[o][r] = W[(size_t)o * 4160 + f * 64 + r];
        }
        __syncthreads();
#pragma unroll
        for (int half = 0; half < 2; ++half) {
            const int u8   = half * 256 + t;
            const int lane = u8 & 63;
            const int kk   = (u8 >> 6) & 1;
            const int nt   = u8 >> 7;
            const int o    = nt * 16 + (lane & 15);
            const int rb   = ((lane >> 4) << 3) + kk * 32;
            f32x4 a = *(const f32x4*)&ws[o][rb];
            f32x4 b = *(const f32x4*)&ws[o][rb + 4];
            unsigned short v[8];
            v[0] = (unsigned short)f2bf(a[0]); v[1] = (unsigned short)f2bf(a[1]);
            v[2] = (unsigned short)f2bf(a[2]); v[3] = (unsigned short)f2bf(a[3]);
            v[4] = (unsigned short)f2bf(b[0]); v[5] = (unsigned short)f2bf(b[1]);
            v[6] = (unsigned short)f2bf(b[2]); v[7] = (unsigned short)f2bf(b[3]);
            const int dst = ((nt * 65 + f) * 2 + kk) * 64 + lane;
            *(bf16x8*)(Wpk + (size_t)dst * 8) = *(bf16x8*)v;
        }
    } else {
#pragma unroll
        for (int i = 0; i < 16; ++i) {
            const int u = i * 256 + t;
            float sd = std_[u];
            float mn = mean[u];
            float th = tanhf(tt[u]);
            float s  = 1.2011224087864498f / sd;  // sqrt(log2(e)) / std
            float4 p;
            p.x = s;
            p.y = mn * s;
            p.z = th;
            p.w = 0.5f * (1.0f - th);
            ((float4*)prm)[u] = p;
        }
    }
}

// ---------------------------------------------------------------------------
// Main fused kernel: block = 64 batch rows, 256 threads (4 waves).
// Stage 0: transpose X slab into LDS xt[f][row].
// Stage 1: wave w computes fire for rows 16w..16w+15 (lane = rule r),
//          x via wave-uniform s_load, pk-f32 math.
// Stage 2: wave w = nt owns cols [16nt,16nt+16) x ALL 64 rows (4 mrow tiles).
//          ONE W-fragment stream feeds 4 MFMA row-tiles (4x W-traffic reuse
//          vs round 4 — this is the whole point of this round).
// ---------------------------------------------------------------------------
__global__ __launch_bounds__(256, 2) void fq_main(
        const float* __restrict__ X,
        const float4* __restrict__ prm,
        const bf16x8* __restrict__ Wp,
        float* __restrict__ out)
{
    __shared__ __align__(16) float xt[64][68];        // [f][row]
    __shared__ __align__(16) float fire_lds[64][68];  // [row][r]
    __shared__ float rinv[BLOCK_B];

    const int t    = threadIdx.x;
    const int lane = t & 63;
    const int w    = __builtin_amdgcn_readfirstlane(t >> 6);  // wave 0..3 (= nt)
    const int b0   = blockIdx.x * BLOCK_B;

    // ---- stage 0: transpose X slab into xt (coalesced reads) ---------------
    {
        const int f4 = (t & 15) * 4;
        const int r0 = t >> 4;           // 0..15
#pragma unroll
        for (int it = 0; it < 4; ++it) {
            const int row = r0 + 16 * it;
            float4 xv = *(const float4*)(X + (size_t)(b0 + row) * 64 + f4);
            xt[f4 + 0][row] = xv.x;
            xt[f4 + 1][row] = xv.y;
            xt[f4 + 2][row] = xv.z;
            xt[f4 + 3][row] = xv.w;
        }
    }

    // ---- stage 1: firing strengths, rows 16w..16w+15, lane = r -------------
    {
        f32x2 fire2[8];
#pragma unroll
        for (int i = 0; i < 8; ++i) fire2[i] = (f32x2){1.f, 1.f};
        const float* Xw = X + (size_t)(b0 + 16 * w) * 64;
#pragma unroll 2
        for (int f = 0; f < F; ++f) {
            float4 p = prm[f * 64 + lane];    // {s, mn*s, t, c}
            f32x2 t2 = (f32x2){p.z, p.z};
            f32x2 c2 = (f32x2){p.w, p.w};
#pragma unroll
            for (int i = 0; i < 8; ++i) {
                float x0 = Xw[(2 * i) * 64 + f];      // wave-uniform -> s_load
                float x1 = Xw[(2 * i + 1) * 64 + f];
                f32x2 z;
                z.x = __builtin_fmaf(x0, p.x, -p.y);
                z.y = __builtin_fmaf(x1, p.x, -p.y);
                f32x2 nz = -(z * z);
                f32x2 g;
                g.x = __builtin_amdgcn_exp2f(nz.x);
                g.y = __builtin_amdgcn_exp2f(nz.y);
                fire2[i] *= g * t2 + c2;
            }
        }
#pragma unroll
        for (int i = 0; i < 8; ++i) {
            fire_lds[16 * w + 2 * i][lane]     = fire2[i].x;
            fire_lds[16 * w + 2 * i + 1][lane] = fire2[i].y;
        }
    }
    __syncthreads();

    // ---- row sums: 4 threads per row, shuffle-reduce -----------------------
    {
        const int row = t >> 2;
        const int c16 = (t & 3) * 16;
        f32x4 s0 = *(const f32x4*)&fire_lds[row][c16];
        f32x4 s1 = *(const f32x4*)&fire_lds[row][c16 + 4];
        f32x4 s2 = *(const f32x4*)&fire_lds[row][c16 + 8];
        f32x4 s3 = *(const f32x4*)&fire_lds[row][c16 + 12];
        float s = ((s0[0] + s0[1]) + (s0[2] + s0[3])) +
                  ((s1[0] + s1[1]) + (s1[2] + s1[3])) +
                  ((s2[0] + s2[1]) + (s2[2] + s2[3])) +
                  ((s3[0] + s3[1]) + (s3[2] + s3[3]));
        s += __shfl_xor(s, 1);
        s += __shfl_xor(s, 2);
        if ((t & 3) == 0) rinv[row] = 1.0f / s;
    }
    __syncthreads();

    // ---- stage 2: 4 row-tiles per wave, one W stream ------------------------
    const int m_in = lane & 15;
    const int quad = lane >> 4;
    const int nt   = w;
    const int q8   = quad * 8;

    bf16x8 wfrag[4][2];   // [mrow][kk]
#pragma unroll
    for (int m = 0; m < 4; ++m) {
        const int myrow = 16 * m + m_in;
        const float rs  = rinv[myrow];
#pragma unroll
        for (int kk = 0; kk < 2; ++kk) {
            f32x4 a = *(const f32x4*)&fire_lds[myrow][q8 + kk * 32];
            f32x4 b = *(const f32x4*)&fire_lds[myrow][q8 + kk * 32 + 4];
            wfrag[m][kk][0] = f2bf(a[0] * rs); wfrag[m][kk][1] = f2bf(a[1] * rs);
            wfrag[m][kk][2] = f2bf(a[2] * rs); wfrag[m][kk][3] = f2bf(a[3] * rs);
            wfrag[m][kk][4] = f2bf(b[0] * rs); wfrag[m][kk][5] = f2bf(b[1] * rs);
            wfrag[m][kk][6] = f2bf(b[2] * rs); wfrag[m][kk][7] = f2bf(b[3] * rs);
        }
    }

    const bf16x8* wpb = Wp + (size_t)(nt * 130) * 64 + lane;

    f32x4 acc[4];
#pragma unroll
    for (int m = 0; m < 4; ++m) acc[m] = (f32x4){0.f, 0.f, 0.f, 0.f};
    const f32x4 z4 = (f32x4){0.f, 0.f, 0.f, 0.f};

#pragma unroll 4
    for (int f = 0; f < F; ++f) {
        bf16x8 bb0 = wpb[(2 * f) * 64];
        bf16x8 bb1 = wpb[(2 * f + 1) * 64];
#pragma unroll
        for (int m = 0; m < 4; ++m) {
            f32x4 U = __builtin_amdgcn_mfma_f32_16x16x32_bf16(wfrag[m][0], bb0, z4, 0, 0, 0);
            U = __builtin_amdgcn_mfma_f32_16x16x32_bf16(wfrag[m][1], bb1, U, 0, 0, 0);
            f32x4 xv = *(const f32x4*)&xt[f][16 * m + quad * 4];  // broadcast b128
#pragma unroll
            for (int reg = 0; reg < 4; ++reg)
                acc[m][reg] = __builtin_fmaf(xv[reg], U[reg], acc[m][reg]);
        }
    }

    // bias column (Xa[:,64] = 1): acc += wn @ B_64
    {
        bf16x8 bb0 = wpb[128 * 64];
        bf16x8 bb1 = wpb[129 * 64];
#pragma unroll
        for (int m = 0; m < 4; ++m) {
            f32x4 U = __builtin_amdgcn_mfma_f32_16x16x32_bf16(wfrag[m][0], bb0, z4, 0, 0, 0);
            U = __builtin_amdgcn_mfma_f32_16x16x32_bf16(wfrag[m][1], bb1, U, 0, 0, 0);
#pragma unroll
            for (int reg = 0; reg < 4; ++reg)
                acc[m][reg] += U[reg];
        }
    }

    // epilogue: C/D layout col = lane&15, row = quad*4 + reg
#pragma unroll
    for (int m = 0; m < 4; ++m)
#pragma unroll
        for (int reg = 0; reg < 4; ++reg) {
            const int row = b0 + 16 * m + quad * 4 + reg;
            out[(size_t)row * 64 + nt * 16 + m_in] = acc[m][reg];
        }
}

extern "C" void kernel_launch(void* const* d_in, const int* in_sizes, int n_in,
                              void* d_out, int out_size, void* d_ws, size_t ws_size,
                              hipStream_t stream) {
    const float* X    = (const float*)d_in[0];
    const float* tt   = (const float*)d_in[1];
    const float* mean = (const float*)d_in[2];
    const float* std_ = (const float*)d_in[3];
    const float* W    = (const float*)d_in[4];
    float* out = (float*)d_out;

    // workspace: prm (float4 x 4096 = 64 KiB) | Wpk (bf16 x 65*512*8 = 520 KiB)
    float* prm = (float*)d_ws;
    unsigned short* Wpk = (unsigned short*)((char*)d_ws + 65536);

    fq_prep<<<66, 256, 0, stream>>>(tt, mean, std_, W, prm, Wpk);

    const int nblocks = 32768 / BLOCK_B;  // 512 blocks x 256 thr = 2048 waves
    fq_main<<<nblocks, 256, 0, stream>>>(X, (const float4*)prm,
                                         (const bf16x8*)Wpk, out);
}